// Round 3
// baseline (306.695 us; speedup 1.0000x reference)
//
#include <hip/hip_runtime.h>
#include <hip/hip_bf16.h>

#define DDIM 256
#define NROWS 8192
#define NTILES 16          // 32-col B tiles per block (512 cols)

typedef __attribute__((ext_vector_type(8))) __bf16 bf16x8;
typedef __attribute__((ext_vector_type(4))) float floatx4;

// async global->LDS, 16B per lane. LDS dest is wave-uniform base + lane*16.
__device__ __forceinline__ void async16(const void* g, void* l) {
    __builtin_amdgcn_global_load_lds(
        (const __attribute__((address_space(1))) unsigned int*)g,
        (__attribute__((address_space(3))) unsigned int*)l,
        16, 0, 0);
}

// raw v_exp_f32: returns 2^x (one transcendental)
__device__ __forceinline__ float fexp2(float x) {
    float r; asm("v_exp_f32 %0, %1" : "=v"(r) : "v"(x)); return r;
}

// Kernel 1: L2-normalize rows of U and P to bf16, compute pos_sim, zero
// rowsum / out / ticket counter. One wave per row.
__global__ __launch_bounds__(256) void normalize_kernel(
    const float* __restrict__ U, const float* __restrict__ P,
    unsigned short* __restrict__ Un, unsigned short* __restrict__ Pn,
    float* __restrict__ possim, float* __restrict__ rowsum,
    float* __restrict__ out, int* __restrict__ counter)
{
    if (blockIdx.x == 0 && threadIdx.x == 0) { out[0] = 0.0f; counter[0] = 0; }
    const int lane = threadIdx.x & 63;
    const int row  = blockIdx.x * 4 + (threadIdx.x >> 6);
    const size_t base = (size_t)row * DDIM + lane * 4;
    const float4 u4 = *(const float4*)(U + base);
    const float4 p4 = *(const float4*)(P + base);
    float su = u4.x*u4.x + u4.y*u4.y + u4.z*u4.z + u4.w*u4.w;
    float sp = p4.x*p4.x + p4.y*p4.y + p4.z*p4.z + p4.w*p4.w;
    float up = u4.x*p4.x + u4.y*p4.y + u4.z*p4.z + u4.w*p4.w;
    #pragma unroll
    for (int d = 1; d < 64; d <<= 1) {
        su += __shfl_xor(su, d);
        sp += __shfl_xor(sp, d);
        up += __shfl_xor(up, d);
    }
    const float iu = rsqrtf(fmaxf(su, 1e-24f));
    const float ip = rsqrtf(fmaxf(sp, 1e-24f));
    if (lane == 0) {
        possim[row] = up * iu * ip;
        rowsum[row] = 0.0f;
    }
    union { ushort4 s4; __hip_bfloat16 h[4]; } cu, cp;
    cu.h[0] = __float2bfloat16(u4.x * iu); cu.h[1] = __float2bfloat16(u4.y * iu);
    cu.h[2] = __float2bfloat16(u4.z * iu); cu.h[3] = __float2bfloat16(u4.w * iu);
    cp.h[0] = __float2bfloat16(p4.x * ip); cp.h[1] = __float2bfloat16(p4.y * ip);
    cp.h[2] = __float2bfloat16(p4.z * ip); cp.h[3] = __float2bfloat16(p4.w * ip);
    *(ushort4*)(Un + base) = cu.s4;
    *(ushort4*)(Pn + base) = cp.s4;
}

// Stage one 32-row (16 KB) B tile into LDS buffer `buf` (0..2); 4 async16/wave.
// boff[jj] = per-lane swizzled byte offset within a tile (iter-invariant).
template<int T, int BUF>
__device__ __forceinline__ void stage_tile(const unsigned short* __restrict__ Bglob,
                                           const unsigned* boff, unsigned short* lds,
                                           int wv)
{
    const char* src = (const char*)Bglob + T * 16384u;
    char* dst = (char*)lds + BUF * 16384 + wv * 4096;
    #pragma unroll
    for (int jj = 0; jj < 4; ++jj)
        async16(src + boff[jj], dst + jj * 1024);
}

// Compute one 32-col tile from LDS buffer J (compile-time -> immediate DS
// offsets). bb[h][ks&1] are per-lane base byte offsets (swizzle pre-folded):
//   addr = bb[h][ks&1] + J*16384 + (ks>>1)*128   (max ~49.1 KB < 64 KiB imm)
// reproducing row*512 + (((ks*4+q)^(m&7))*16).
template<int J>
__device__ __forceinline__ void compute_tile(const unsigned short* lds,
        const unsigned (&bb)[2][2], const bf16x8 (&afr)[2][8],
        float (&rowpart)[2][4])
{
    floatx4 acc[2][2];
    #pragma unroll
    for (int t = 0; t < 2; ++t) {
        acc[t][0] = {0.0f, 0.0f, 0.0f, 0.0f};
        acc[t][1] = {0.0f, 0.0f, 0.0f, 0.0f};
    }
    const char* base = (const char*)lds;
    #pragma unroll
    for (int ks = 0; ks < 8; ++ks) {
        const bf16x8 b0 = *(const bf16x8*)(base + bb[0][ks & 1]
                                           + (J * 16384 + (ks >> 1) * 128));
        const bf16x8 b1 = *(const bf16x8*)(base + bb[1][ks & 1]
                                           + (J * 16384 + (ks >> 1) * 128));
        #pragma unroll
        for (int t = 0; t < 2; ++t) {
            acc[t][0] = __builtin_amdgcn_mfma_f32_16x16x32_bf16(
                afr[t][ks], b0, acc[t][0], 0, 0, 0);
            acc[t][1] = __builtin_amdgcn_mfma_f32_16x16x32_bf16(
                afr[t][ks], b1, acc[t][1], 0, 0, 0);
        }
    }
    // exp(5*sim) = 2^(sim * 5*log2(e)); C/D: col = m, row = q*4 + r (+t*16)
    #pragma unroll
    for (int t = 0; t < 2; ++t)
        #pragma unroll
        for (int h = 0; h < 2; ++h)
            #pragma unroll
            for (int r = 0; r < 4; ++r)
                rowpart[t][r] += fexp2(acc[t][h][r] * 7.2134752044448169f);
}

// Kernel 2: A-in-registers GEMM + exp-rowsum + fused finalize.
// 1024 blocks, 48 KB LDS -> 3 blocks/CU (12 waves/CU), 4 waves,
// wave = 32 rows x full 32-col tile. Block = 128 rows x 512 cols.
// A-frags read directly from global (L2-hot, one-time). B triple-buffered
// 3 x 16 KB, prefetch depth 2, ONE barrier per tile, counted vmcnt(4)
// mid-loop (never 0): tile T's loads were issued two slots (~500+ cyc) ago.
// Slot T (buf T%3): lgkm(0) [my reads of T-1 done] -> vmcnt(4) [T landed,
// T+1 in flight] -> barrier -> stage T+2 into buf (T+2)%3 == (T-1)%3
// [freed by the barrier] -> compute T.
__global__ __launch_bounds__(256, 3) void sim_exp_rowsum(
    const unsigned short* __restrict__ Un,
    const unsigned short* __restrict__ Pn,
    float* __restrict__ rowsum,
    const float* __restrict__ possim,
    int* __restrict__ counter,
    float* __restrict__ out)
{
    __shared__ __align__(16) unsigned short lds[24576];   // 48 KB: 3 x 16 KB B bufs
    __shared__ float ws4[4];
    __shared__ int ticket_s;

    const int tid  = threadIdx.x;
    const int lane = tid & 63;
    const int wv   = tid >> 6;          // 0..3, each wave owns 32 A-rows
    const int m = lane & 15;
    const int q = lane >> 4;

    const int stripe = blockIdx.x >> 4;   // 0..63  (128-row stripes)
    const int cg     = blockIdx.x & 15;   // 0..15  (512-col groups; &7 = XCD)

    // ---- A-frags straight from global (Un is L2/L3-hot, 64 KB per block) ----
    const unsigned short* Arow = Un + (size_t)(stripe * 128 + wv * 32 + m) * DDIM;
    bf16x8 afr[2][8];
    #pragma unroll
    for (int t = 0; t < 2; ++t)
        #pragma unroll
        for (int ks = 0; ks < 8; ++ks)
            afr[t][ks] = *(const bf16x8*)(Arow + t * 16 * DDIM + (ks * 4 + q) * 8);

    // ---- Hoisted per-lane addressing ----
    const int c10 = m & 3, c2 = (m >> 2) & 1;
    unsigned bb[2][2];
    #pragma unroll
    for (int h = 0; h < 2; ++h)
        #pragma unroll
        for (int par = 0; par < 2; ++par)
            bb[h][par] = (unsigned)((h * 16 + m) * 512
                                    + ((q ^ c10) << 4) + ((par ^ c2) << 6));

    // stage offsets: wave stages 8 rows/tile (4 async16); granule swizzle
    // g^(r&7) hoists since tile row base is 0 mod 8.
    const int lrow = lane >> 5, gcol = lane & 31;
    unsigned boff[4];
    #pragma unroll
    for (int jj = 0; jj < 4; ++jj) {
        const int r = wv * 8 + jj * 2 + lrow;
        const int gg = gcol ^ (r & 7);
        boff[jj] = (unsigned)(r * 512 + gg * 16);
    }

    const unsigned short* Bglob = Pn + (size_t)(cg * 512) * DDIM;
    float rowpart[2][4] = {{0.f, 0.f, 0.f, 0.f}, {0.f, 0.f, 0.f, 0.f}};

    // ---- Prologue: fill bufs 0,1 (A-loads older than these in vmcnt order) --
    stage_tile<0, 0>(Bglob, boff, lds, wv);
    stage_tile<1, 1>(Bglob, boff, lds, wv);

    // ---- 16 fully-unrolled slots, one barrier each ----
#define SLOT(T, NW)                                                          \
    do {                                                                     \
        asm volatile("s_waitcnt lgkmcnt(0)" ::: "memory");                   \
        asm volatile("s_waitcnt vmcnt(" #NW ")" ::: "memory");               \
        __builtin_amdgcn_s_barrier();                                        \
        if constexpr ((T) + 2 < NTILES)                                      \
            stage_tile<((T) + 2 < NTILES) ? (T) + 2 : 0,                     \
                       ((T) + 2) % 3>(Bglob, boff, lds, wv);                 \
        compute_tile<(T) % 3>(lds, bb, afr, rowpart);                        \
    } while (0)

    // Slot 0's vmcnt(4) also drains the 16 A-loads (they are older).
    SLOT(0, 4);  SLOT(1, 4);  SLOT(2, 4);  SLOT(3, 4);
    SLOT(4, 4);  SLOT(5, 4);  SLOT(6, 4);  SLOT(7, 4);
    SLOT(8, 4);  SLOT(9, 4);  SLOT(10, 4); SLOT(11, 4);
    SLOT(12, 4); SLOT(13, 4); SLOT(14, 4); SLOT(15, 0);
#undef SLOT

    // ---- Epilogue: reduce 16 column-lanes, one atomic per row per wave ----
    #pragma unroll
    for (int t = 0; t < 2; ++t) {
        #pragma unroll
        for (int r = 0; r < 4; ++r) {
            float s = rowpart[t][r];
            s += __shfl_xor(s, 1);
            s += __shfl_xor(s, 2);
            s += __shfl_xor(s, 4);
            s += __shfl_xor(s, 8);
            if (m == 0) {
                const int grow = stripe * 128 + wv * 32 + t * 16 + q * 4 + r;
                atomicAdd(&rowsum[grow], s);
            }
        }
    }

    // ---- Fused finalize: last block computes the loss ----
    __threadfence();
    __syncthreads();   // this block's atomics are visible
    if (tid == 0)
        ticket_s = __hip_atomic_fetch_add(counter, 1, __ATOMIC_ACQ_REL,
                                          __HIP_MEMORY_SCOPE_AGENT);
    __syncthreads();
    if (ticket_s == 1023) {
        float part = 0.0f;
        for (int i = tid; i < NROWS; i += 256) {
            const float rs = __hip_atomic_load(&rowsum[i], __ATOMIC_RELAXED,
                                               __HIP_MEMORY_SCOPE_AGENT);
            part += __logf(rs) - 5.0f * possim[i];
        }
        #pragma unroll
        for (int d = 1; d < 64; d <<= 1) part += __shfl_xor(part, d);
        if (lane == 0) ws4[wv] = part;
        __syncthreads();
        if (tid == 0)
            out[0] = (ws4[0] + ws4[1] + ws4[2] + ws4[3]) * (1.0f / (float)NROWS);
    }
}

extern "C" void kernel_launch(void* const* d_in, const int* in_sizes, int n_in,
                              void* d_out, int out_size, void* d_ws, size_t ws_size,
                              hipStream_t stream) {
    const float* U = (const float*)d_in[0];
    const float* P = (const float*)d_in[1];
    float* out = (float*)d_out;
    char* ws = (char*)d_ws;
    // ws: Un bf16 (4 MB) | Pn bf16 (4 MB) | rowsum f32 (32 KB) | possim f32 (32 KB) | counter
    unsigned short* Un = (unsigned short*)ws;
    unsigned short* Pn = (unsigned short*)(ws + 4194304);
    float* rowsum = (float*)(ws + 8388608);
    float* possim = (float*)(ws + 8388608 + 32768);
    int* counter  = (int*)(ws + 8388608 + 65536);

    normalize_kernel<<<NROWS / 4, 256, 0, stream>>>(U, P, Un, Pn, possim, rowsum,
                                                    out, counter);
    sim_exp_rowsum<<<1024, 256, 0, stream>>>(Un, Pn, rowsum, possim, counter, out);
}

// Round 4
// 169.199 us; speedup vs baseline: 1.8126x; 1.8126x over previous
//
#include <hip/hip_runtime.h>
#include <hip/hip_bf16.h>

#define DDIM 256
#define NROWS 8192

typedef __attribute__((ext_vector_type(8))) __bf16 bf16x8;
typedef __attribute__((ext_vector_type(4))) float floatx4;

// async global->LDS, 16B per lane. LDS dest is wave-uniform base + lane*16.
__device__ __forceinline__ void async16(const void* g, void* l) {
    __builtin_amdgcn_global_load_lds(
        (const __attribute__((address_space(1))) unsigned int*)g,
        (__attribute__((address_space(3))) unsigned int*)l,
        16, 0, 0);
}

// raw v_exp_f32: returns 2^x (one transcendental)
__device__ __forceinline__ float fexp2(float x) {
    float r; asm("v_exp_f32 %0, %1" : "=v"(r) : "v"(x)); return r;
}

// Kernel 1: L2-normalize rows of U and P to bf16, compute pos_sim, zero
// rowsum / out / ticket counter. One wave per row.
__global__ __launch_bounds__(256) void normalize_kernel(
    const float* __restrict__ U, const float* __restrict__ P,
    unsigned short* __restrict__ Un, unsigned short* __restrict__ Pn,
    float* __restrict__ possim, float* __restrict__ rowsum,
    float* __restrict__ out, int* __restrict__ counter)
{
    if (blockIdx.x == 0 && threadIdx.x == 0) { out[0] = 0.0f; counter[0] = 0; }
    const int lane = threadIdx.x & 63;
    const int row  = blockIdx.x * 4 + (threadIdx.x >> 6);
    const size_t base = (size_t)row * DDIM + lane * 4;
    const float4 u4 = *(const float4*)(U + base);
    const float4 p4 = *(const float4*)(P + base);
    float su = u4.x*u4.x + u4.y*u4.y + u4.z*u4.z + u4.w*u4.w;
    float sp = p4.x*p4.x + p4.y*p4.y + p4.z*p4.z + p4.w*p4.w;
    float up = u4.x*p4.x + u4.y*p4.y + u4.z*p4.z + u4.w*p4.w;
    #pragma unroll
    for (int d = 1; d < 64; d <<= 1) {
        su += __shfl_xor(su, d);
        sp += __shfl_xor(sp, d);
        up += __shfl_xor(up, d);
    }
    const float iu = rsqrtf(fmaxf(su, 1e-24f));
    const float ip = rsqrtf(fmaxf(sp, 1e-24f));
    if (lane == 0) {
        possim[row] = up * iu * ip;
        rowsum[row] = 0.0f;
    }
    union { ushort4 s4; __hip_bfloat16 h[4]; } cu, cp;
    cu.h[0] = __float2bfloat16(u4.x * iu); cu.h[1] = __float2bfloat16(u4.y * iu);
    cu.h[2] = __float2bfloat16(u4.z * iu); cu.h[3] = __float2bfloat16(u4.w * iu);
    cp.h[0] = __float2bfloat16(p4.x * ip); cp.h[1] = __float2bfloat16(p4.y * ip);
    cp.h[2] = __float2bfloat16(p4.z * ip); cp.h[3] = __float2bfloat16(p4.w * ip);
    *(ushort4*)(Un + base) = cu.s4;
    *(ushort4*)(Pn + base) = cp.s4;
}

// Stage rows_per_wave rows (full K=256, 512 B/row) per wave into LDS at l,
// linear layout with granule swizzle: stored granule position g holds logical
// granule g ^ (row&7). One async16 covers 2 rows (64 lanes x 16 B).
// Proven in R0 (86 us). Offsets recomputed per call (transient VALU, no regs).
__device__ __forceinline__ void stage_rows(const unsigned short* __restrict__ g,
                                           unsigned short* l,
                                           int wv, int lane,
                                           int rows_per_wave, int ninstr)
{
    const int lrow = lane >> 5;       // 0..1
    const int gcol = lane & 31;       // granule 0..31
    const int r0 = wv * rows_per_wave;
    #pragma unroll
    for (int j = 0; j < 4; ++j) {
        const int rb = r0 + j * 2;
        const int r  = rb + lrow;
        const int gg = gcol ^ (r & 7);
        async16(g + (size_t)r * DDIM + gg * 8, l + (size_t)rb * DDIM);
    }
}

// Kernel 2: A-in-registers GEMM + exp-rowsum + fused finalize.
// R0's exact slot discipline at 2x the residency:
//   512 blocks of 512 threads (8 waves). Block = 256 rows x 512 cols.
//   Wave = 32 rows x full 64-col tile (afr[2][8] = 64 regs, A direct from
//   global -- L2/L3-hot, one-time). B double-buffered 2 x 32 KB (64-col
//   tiles, LONG compute phase), ONE __syncthreads per slot, stage of tile
//   i+1 issued right after barrier i and consumed at barrier i+1 -> a full
//   compute phase (~1000 cy) in flight, so the barrier's implicit vmcnt
//   drain is cheap (the R0-proven pattern; R2 showed short phases break it).
//   64.5 KB LDS -> 2 blocks/CU = 16 waves/CU = 4 waves/SIMD (2x R0).
//   Register budget ~115 (<128 cap from __launch_bounds__(512,4)):
//   acc[2][2] with the slot split in two 32-col halves (no extra barriers),
//   B-frag addressing collapsed to 2 persistent regs + immediates.
__global__ __launch_bounds__(512, 4) void sim_exp_rowsum(
    const unsigned short* __restrict__ Un,
    const unsigned short* __restrict__ Pn,
    float* __restrict__ rowsum,
    const float* __restrict__ possim,
    int* __restrict__ counter,
    float* __restrict__ out)
{
    __shared__ __align__(16) unsigned short lds[32768];   // 64 KB: 2 x 32 KB B bufs
    __shared__ float ws8[8];
    __shared__ int ticket_s;

    const int tid  = threadIdx.x;
    const int lane = tid & 63;
    const int wv   = tid >> 6;          // 0..7, each wave owns 32 A-rows
    const int m = lane & 15;
    const int q = lane >> 4;

    const int stripe = blockIdx.x >> 4;   // 0..31  (256-row stripes)
    const int cg     = blockIdx.x & 15;   // 0..15  (512-col groups; &7 = XCD)

    // ---- A-frags straight from global (one-time, 128 KB per block) ----
    // row = stripe*256 + wv*32 + t*16 + m ; bytes (ks*4+q)*16 (linear)
    const unsigned short* Arow = Un + (size_t)(stripe * 256 + wv * 32 + m) * DDIM;
    bf16x8 afr[2][8];
    #pragma unroll
    for (int t = 0; t < 2; ++t)
        #pragma unroll
        for (int ks = 0; ks < 8; ++ks)
            afr[t][ks] = *(const bf16x8*)(Arow + t * 16 * DDIM + (ks * 4 + q) * 8);

    // ---- B-frag addressing: 2 persistent regs, rest immediates ----
    // byte addr within buf = bbp[ks&1] + j*8192 + (ks>>1)*128  (j = 16-col
    // group 0..3), reproducing row*512 + ((ks*4+q)^(m&7))*16 for row=j*16+m.
    const int c10 = m & 3, c2 = (m >> 2) & 1;
    unsigned bbp[2];
    #pragma unroll
    for (int par = 0; par < 2; ++par)
        bbp[par] = (unsigned)(m * 512 + ((q ^ c10) << 4) + ((par ^ c2) << 6));

    const unsigned short* Bglob = Pn + (size_t)(cg * 512) * DDIM;
    float rowpart[2][4] = {{0.f, 0.f, 0.f, 0.f}, {0.f, 0.f, 0.f, 0.f}};

    // ---- Prologue: stage tile 0 into buf 0 ----
    stage_rows(Bglob, lds, wv, lane, 8, 4);

    // ---- Main loop: 8 col-tiles of 64, R0 slot discipline ----
    for (int i = 0; i < 8; ++i) {
        __syncthreads();   // drains tile-i loads (in flight through slot i-1)
        if (i < 7)
            stage_rows(Bglob + (size_t)(i + 1) * 64 * DDIM,
                       lds + ((i + 1) & 1) * 16384, wv, lane, 8, 4);
        const char* Bp = (const char*)(lds + (i & 1) * 16384);

        #pragma unroll
        for (int hh = 0; hh < 2; ++hh) {        // two 32-col halves, no sync
            floatx4 acc[2][2];
            #pragma unroll
            for (int t = 0; t < 2; ++t) {
                acc[t][0] = {0.0f, 0.0f, 0.0f, 0.0f};
                acc[t][1] = {0.0f, 0.0f, 0.0f, 0.0f};
            }
            #pragma unroll
            for (int ks = 0; ks < 8; ++ks) {
                const bf16x8 b0 = *(const bf16x8*)(Bp + bbp[ks & 1]
                        + ((hh * 2 + 0) * 8192 + (ks >> 1) * 128));
                const bf16x8 b1 = *(const bf16x8*)(Bp + bbp[ks & 1]
                        + ((hh * 2 + 1) * 8192 + (ks >> 1) * 128));
                #pragma unroll
                for (int t = 0; t < 2; ++t) {
                    acc[t][0] = __builtin_amdgcn_mfma_f32_16x16x32_bf16(
                        afr[t][ks], b0, acc[t][0], 0, 0, 0);
                    acc[t][1] = __builtin_amdgcn_mfma_f32_16x16x32_bf16(
                        afr[t][ks], b1, acc[t][1], 0, 0, 0);
                }
            }
            // exp(5*sim) = 2^(sim*5*log2 e); C/D: col = m, row = q*4+r (+t*16)
            #pragma unroll
            for (int t = 0; t < 2; ++t)
                #pragma unroll
                for (int h = 0; h < 2; ++h)
                    #pragma unroll
                    for (int r = 0; r < 4; ++r)
                        rowpart[t][r] += fexp2(acc[t][h][r] * 7.2134752044448169f);
        }
    }

    // ---- Epilogue: reduce 16 column-lanes, one atomic per row per wave ----
    #pragma unroll
    for (int t = 0; t < 2; ++t) {
        #pragma unroll
        for (int r = 0; r < 4; ++r) {
            float s = rowpart[t][r];
            s += __shfl_xor(s, 1);
            s += __shfl_xor(s, 2);
            s += __shfl_xor(s, 4);
            s += __shfl_xor(s, 8);
            if (m == 0) {
                const int grow = stripe * 256 + wv * 32 + t * 16 + q * 4 + r;
                atomicAdd(&rowsum[grow], s);
            }
        }
    }

    // ---- Fused finalize: last block computes the loss ----
    __threadfence();
    __syncthreads();   // this block's atomics are visible
    if (tid == 0)
        ticket_s = __hip_atomic_fetch_add(counter, 1, __ATOMIC_ACQ_REL,
                                          __HIP_MEMORY_SCOPE_AGENT);
    __syncthreads();
    if (ticket_s == 511) {
        float part = 0.0f;
        for (int i = tid; i < NROWS; i += 512) {
            const float rs = __hip_atomic_load(&rowsum[i], __ATOMIC_RELAXED,
                                               __HIP_MEMORY_SCOPE_AGENT);
            part += __logf(rs) - 5.0f * possim[i];
        }
        #pragma unroll
        for (int d = 1; d < 64; d <<= 1) part += __shfl_xor(part, d);
        if (lane == 0) ws8[wv] = part;
        __syncthreads();
        if (tid == 0) {
            float tot = 0.0f;
            #pragma unroll
            for (int w = 0; w < 8; ++w) tot += ws8[w];
            out[0] = tot * (1.0f / (float)NROWS);
        }
    }
}

extern "C" void kernel_launch(void* const* d_in, const int* in_sizes, int n_in,
                              void* d_out, int out_size, void* d_ws, size_t ws_size,
                              hipStream_t stream) {
    const float* U = (const float*)d_in[0];
    const float* P = (const float*)d_in[1];
    float* out = (float*)d_out;
    char* ws = (char*)d_ws;
    // ws: Un bf16 (4 MB) | Pn bf16 (4 MB) | rowsum f32 (32 KB) | possim f32 (32 KB) | counter
    unsigned short* Un = (unsigned short*)ws;
    unsigned short* Pn = (unsigned short*)(ws + 4194304);
    float* rowsum = (float*)(ws + 8388608);
    float* possim = (float*)(ws + 8388608 + 32768);
    int* counter  = (int*)(ws + 8388608 + 65536);

    normalize_kernel<<<NROWS / 4, 256, 0, stream>>>(U, P, Un, Pn, possim, rowsum,
                                                    out, counter);
    sim_exp_rowsum<<<512, 512, 0, stream>>>(Un, Pn, rowsum, possim, counter, out);
}

// Round 5
// 149.216 us; speedup vs baseline: 2.0554x; 1.1339x over previous
//
#include <hip/hip_runtime.h>
#include <hip/hip_bf16.h>

#define DDIM 256
#define NROWS 8192

typedef __attribute__((ext_vector_type(8))) __bf16 bf16x8;
typedef __attribute__((ext_vector_type(4))) float floatx4;

// async global->LDS, 16B per lane. LDS dest is wave-uniform base + lane*16.
__device__ __forceinline__ void async16(const void* g, void* l) {
    __builtin_amdgcn_global_load_lds(
        (const __attribute__((address_space(1))) unsigned int*)g,
        (__attribute__((address_space(3))) unsigned int*)l,
        16, 0, 0);
}

// Stage rows_per_wave rows (full K=256, 512 B/row) per wave into LDS at l,
// linear layout with granule swizzle: stored granule position g holds logical
// granule g ^ (row&7). One async16 covers 2 rows (64 lanes x 16 B).
__device__ __forceinline__ void stage_rows(const unsigned short* __restrict__ g,
                                           unsigned short* l,
                                           int wv, int lane,
                                           int rows_per_wave, int ninstr)
{
    const int lrow = lane >> 5;       // 0..1
    const int gcol = lane & 31;       // granule 0..31
    const int r0 = wv * rows_per_wave;
    for (int j = 0; j < ninstr; ++j) {
        const int rb = r0 + j * 2;
        const int r  = rb + lrow;
        const int gg = gcol ^ (r & 7);
        async16(g + (size_t)r * DDIM + gg * 8, l + (size_t)rb * DDIM);
    }
}

__device__ __forceinline__ bf16x8 frag(const unsigned short* base, int row,
                                       int ks, int q, int m)
{
    return *(const bf16x8*)&base[(size_t)row * DDIM
                                 + (((ks * 4 + q) ^ (m & 7)) * 8)];
}

// Kernel 1: L2-normalize rows of U and P to bf16, compute pos_sim, zero
// rowsum / out / ticket counter. One wave per row.
__global__ __launch_bounds__(256) void normalize_kernel(
    const float* __restrict__ U, const float* __restrict__ P,
    unsigned short* __restrict__ Un, unsigned short* __restrict__ Pn,
    float* __restrict__ possim, float* __restrict__ rowsum,
    float* __restrict__ out, int* __restrict__ counter)
{
    if (blockIdx.x == 0 && threadIdx.x == 0) { out[0] = 0.0f; counter[0] = 0; }
    const int lane = threadIdx.x & 63;
    const int row  = blockIdx.x * 4 + (threadIdx.x >> 6);
    const size_t base = (size_t)row * DDIM + lane * 4;
    const float4 u4 = *(const float4*)(U + base);
    const float4 p4 = *(const float4*)(P + base);
    float su = u4.x*u4.x + u4.y*u4.y + u4.z*u4.z + u4.w*u4.w;
    float sp = p4.x*p4.x + p4.y*p4.y + p4.z*p4.z + p4.w*p4.w;
    float up = u4.x*p4.x + u4.y*p4.y + u4.z*p4.z + u4.w*p4.w;
    #pragma unroll
    for (int d = 1; d < 64; d <<= 1) {
        su += __shfl_xor(su, d);
        sp += __shfl_xor(sp, d);
        up += __shfl_xor(up, d);
    }
    const float iu = rsqrtf(fmaxf(su, 1e-24f));
    const float ip = rsqrtf(fmaxf(sp, 1e-24f));
    if (lane == 0) {
        possim[row] = up * iu * ip;
        rowsum[row] = 0.0f;
    }
    union { ushort4 s4; __hip_bfloat16 h[4]; } cu, cp;
    cu.h[0] = __float2bfloat16(u4.x * iu); cu.h[1] = __float2bfloat16(u4.y * iu);
    cu.h[2] = __float2bfloat16(u4.z * iu); cu.h[3] = __float2bfloat16(u4.w * iu);
    cp.h[0] = __float2bfloat16(p4.x * ip); cp.h[1] = __float2bfloat16(p4.y * ip);
    cp.h[2] = __float2bfloat16(p4.z * ip); cp.h[3] = __float2bfloat16(p4.w * ip);
    *(ushort4*)(Un + base) = cu.s4;
    *(ushort4*)(Pn + base) = cp.s4;
}

// Kernel 2: persistent-A GEMM + exp-rowsum + fused finalize.
// R0 structure (proven 86 us) with ONE change: the per-slot 8-ks inner loop
// is split into 4 barrier-fenced phases of {4 ds_reads -> s_barrier ->
// lgkmcnt(0)+sched_barrier -> setprio(1) -> 16 MFMA -> setprio(0)} (T3/T5
// port). All phases read the same stable B buffer, so the intra-slot
// barriers are pure scheduling fences -- no hazard, no correctness coupling.
// Everything else (512 blocks, 2/CU, 4 waves 2x2, 64-col tiles, A staged to
// regs via LDS, stage-right-after-barrier, one semantic barrier per slot)
// is byte-identical to R0.
__global__ __launch_bounds__(256, 2) void sim_exp_rowsum(
    const unsigned short* __restrict__ Un,
    const unsigned short* __restrict__ Pn,
    float* __restrict__ rowsum,
    const float* __restrict__ possim,
    int* __restrict__ counter,
    float* __restrict__ out)
{
    __shared__ __align__(16) unsigned short lds[32768];   // 64 KB: 2 x 32 KB B bufs; A transient
    __shared__ float ws4[4];
    __shared__ int ticket_s;

    const int tid  = threadIdx.x;
    const int lane = tid & 63;
    const int wv   = tid >> 6;
    const int wr   = wv >> 1, wc = wv & 1;
    const int m = lane & 15;
    const int q = lane >> 4;

    const int stripe = blockIdx.x >> 3;   // 0..63
    const int oct    = blockIdx.x & 7;    // 0..7

    // ---- Prologue: stage A stripe (128 rows), pull A-frags to registers ----
    const unsigned short* Aglob = Un + (size_t)stripe * 128 * DDIM;
    stage_rows(Aglob, lds, wv, lane, 32, 16);
    __syncthreads();

    bf16x8 afr[4][8];
    #pragma unroll
    for (int t = 0; t < 4; ++t)
        #pragma unroll
        for (int ks = 0; ks < 8; ++ks)
            afr[t][ks] = frag(lds, wr * 64 + t * 16 + m, ks, q, m);
    __syncthreads();   // all waves have A in regs; LDS free for B bufs

    // ---- Main loop: 16 col-tiles of 64, B double-buffered ----
    const unsigned short* Bglob = Pn + (size_t)(oct * 1024) * DDIM;
    float rowpart[4][4];
    #pragma unroll
    for (int t = 0; t < 4; ++t)
        #pragma unroll
        for (int r = 0; r < 4; ++r)
            rowpart[t][r] = 0.0f;

    stage_rows(Bglob, lds, wv, lane, 16, 8);   // tile 0 -> buf0

    for (int i = 0; i < 16; ++i) {
        __syncthreads();   // drains B[i] loads (in flight through iter i-1)
        if (i < 15)
            stage_rows(Bglob + (size_t)(i + 1) * 64 * DDIM,
                       lds + ((i + 1) & 1) * 16384, wv, lane, 16, 8);
        const unsigned short* Bp = lds + (i & 1) * 16384;

        floatx4 acc[4][2];
        #pragma unroll
        for (int t = 0; t < 4; ++t) {
            acc[t][0] = {0.0f, 0.0f, 0.0f, 0.0f};
            acc[t][1] = {0.0f, 0.0f, 0.0f, 0.0f};
        }
        // 4 phases of 2 ks-steps each: reads issued BEFORE the phase fence
        // (overlap prior phase's MFMAs in other waves), MFMA cluster behind
        // lgkm drain at raised priority.
        #pragma unroll
        for (int p = 0; p < 4; ++p) {
            const int k0 = 2 * p, k1 = 2 * p + 1;
            const bf16x8 b00 = frag(Bp, wc * 32 + m,      k0, q, m);
            const bf16x8 b01 = frag(Bp, wc * 32 + 16 + m, k0, q, m);
            const bf16x8 b10 = frag(Bp, wc * 32 + m,      k1, q, m);
            const bf16x8 b11 = frag(Bp, wc * 32 + 16 + m, k1, q, m);
            __builtin_amdgcn_s_barrier();                 // phase fence (no hazard)
            asm volatile("s_waitcnt lgkmcnt(0)" ::: "memory");
            __builtin_amdgcn_sched_barrier(0);
            __builtin_amdgcn_s_setprio(1);
            #pragma unroll
            for (int t = 0; t < 4; ++t) {
                acc[t][0] = __builtin_amdgcn_mfma_f32_16x16x32_bf16(
                    afr[t][k0], b00, acc[t][0], 0, 0, 0);
                acc[t][1] = __builtin_amdgcn_mfma_f32_16x16x32_bf16(
                    afr[t][k0], b01, acc[t][1], 0, 0, 0);
                acc[t][0] = __builtin_amdgcn_mfma_f32_16x16x32_bf16(
                    afr[t][k1], b10, acc[t][0], 0, 0, 0);
                acc[t][1] = __builtin_amdgcn_mfma_f32_16x16x32_bf16(
                    afr[t][k1], b11, acc[t][1], 0, 0, 0);
            }
            __builtin_amdgcn_s_setprio(0);
            __builtin_amdgcn_sched_barrier(0);
        }
        // exp(5*sim) accumulated per-lane; C/D: col = m, row = q*4 + r (+t*16)
        #pragma unroll
        for (int t = 0; t < 4; ++t)
            #pragma unroll
            for (int r = 0; r < 4; ++r)
                rowpart[t][r] += __expf(5.0f * acc[t][0][r])
                               + __expf(5.0f * acc[t][1][r]);
    }

    // ---- Epilogue: reduce 16 column-lanes, one atomic per row per wave ----
    #pragma unroll
    for (int t = 0; t < 4; ++t) {
        #pragma unroll
        for (int r = 0; r < 4; ++r) {
            float s = rowpart[t][r];
            s += __shfl_xor(s, 1);
            s += __shfl_xor(s, 2);
            s += __shfl_xor(s, 4);
            s += __shfl_xor(s, 8);
            if (m == 0) {
                const int grow = stripe * 128 + wr * 64 + t * 16 + q * 4 + r;
                atomicAdd(&rowsum[grow], s);
            }
        }
    }

    // ---- Fused finalize: last block computes the loss ----
    __threadfence();
    __syncthreads();   // vmcnt(0) drain: this block's atomics are visible
    if (tid == 0)
        ticket_s = __hip_atomic_fetch_add(counter, 1, __ATOMIC_ACQ_REL,
                                          __HIP_MEMORY_SCOPE_AGENT);
    __syncthreads();
    if (ticket_s == 511) {
        float part = 0.0f;
        for (int i = tid; i < NROWS; i += 256) {
            const float rs = __hip_atomic_load(&rowsum[i], __ATOMIC_RELAXED,
                                               __HIP_MEMORY_SCOPE_AGENT);
            part += __logf(rs) - 5.0f * possim[i];
        }
        #pragma unroll
        for (int d = 1; d < 64; d <<= 1) part += __shfl_xor(part, d);
        if (lane == 0) ws4[wv] = part;
        __syncthreads();
        if (tid == 0)
            out[0] = (ws4[0] + ws4[1] + ws4[2] + ws4[3]) * (1.0f / (float)NROWS);
    }
}

extern "C" void kernel_launch(void* const* d_in, const int* in_sizes, int n_in,
                              void* d_out, int out_size, void* d_ws, size_t ws_size,
                              hipStream_t stream) {
    const float* U = (const float*)d_in[0];
    const float* P = (const float*)d_in[1];
    float* out = (float*)d_out;
    char* ws = (char*)d_ws;
    // ws: Un bf16 (4 MB) | Pn bf16 (4 MB) | rowsum f32 (32 KB) | possim f32 (32 KB) | counter
    unsigned short* Un = (unsigned short*)ws;
    unsigned short* Pn = (unsigned short*)(ws + 4194304);
    float* rowsum = (float*)(ws + 8388608);
    float* possim = (float*)(ws + 8388608 + 32768);
    int* counter  = (int*)(ws + 8388608 + 65536);

    normalize_kernel<<<NROWS / 4, 256, 0, stream>>>(U, P, Un, Pn, possim, rowsum,
                                                    out, counter);
    sim_exp_rowsum<<<512, 256, 0, stream>>>(Un, Pn, rowsum, possim, counter, out);
}

// Round 6
// 144.556 us; speedup vs baseline: 2.1216x; 1.0322x over previous
//
#include <hip/hip_runtime.h>
#include <hip/hip_bf16.h>

#define DDIM 256
#define NROWS 8192

typedef __attribute__((ext_vector_type(8))) __bf16 bf16x8;
typedef __attribute__((ext_vector_type(4))) float floatx4;

// async global->LDS, 16B per lane. LDS dest is wave-uniform base + lane*16.
__device__ __forceinline__ void async16(const void* g, void* l) {
    __builtin_amdgcn_global_load_lds(
        (const __attribute__((address_space(1))) unsigned int*)g,
        (__attribute__((address_space(3))) unsigned int*)l,
        16, 0, 0);
}

// raw v_exp_f32: returns 2^x (one transcendental)
__device__ __forceinline__ float fexp2(float x) {
    float r; asm("v_exp_f32 %0, %1" : "=v"(r) : "v"(x)); return r;
}

// Kernel 1: L2-normalize rows of U and P to bf16, compute pos_sim, zero
// rowsum / out / ticket counter. One wave per row.
__global__ __launch_bounds__(256) void normalize_kernel(
    const float* __restrict__ U, const float* __restrict__ P,
    unsigned short* __restrict__ Un, unsigned short* __restrict__ Pn,
    float* __restrict__ possim, float* __restrict__ rowsum,
    float* __restrict__ out, int* __restrict__ counter)
{
    if (blockIdx.x == 0 && threadIdx.x == 0) { out[0] = 0.0f; counter[0] = 0; }
    const int lane = threadIdx.x & 63;
    const int row  = blockIdx.x * 4 + (threadIdx.x >> 6);
    const size_t base = (size_t)row * DDIM + lane * 4;
    const float4 u4 = *(const float4*)(U + base);
    const float4 p4 = *(const float4*)(P + base);
    float su = u4.x*u4.x + u4.y*u4.y + u4.z*u4.z + u4.w*u4.w;
    float sp = p4.x*p4.x + p4.y*p4.y + p4.z*p4.z + p4.w*p4.w;
    float up = u4.x*p4.x + u4.y*p4.y + u4.z*p4.z + u4.w*p4.w;
    #pragma unroll
    for (int d = 1; d < 64; d <<= 1) {
        su += __shfl_xor(su, d);
        sp += __shfl_xor(sp, d);
        up += __shfl_xor(up, d);
    }
    const float iu = rsqrtf(fmaxf(su, 1e-24f));
    const float ip = rsqrtf(fmaxf(sp, 1e-24f));
    if (lane == 0) {
        possim[row] = up * iu * ip;
        rowsum[row] = 0.0f;
    }
    union { ushort4 s4; __hip_bfloat16 h[4]; } cu, cp;
    cu.h[0] = __float2bfloat16(u4.x * iu); cu.h[1] = __float2bfloat16(u4.y * iu);
    cu.h[2] = __float2bfloat16(u4.z * iu); cu.h[3] = __float2bfloat16(u4.w * iu);
    cp.h[0] = __float2bfloat16(p4.x * ip); cp.h[1] = __float2bfloat16(p4.y * ip);
    cp.h[2] = __float2bfloat16(p4.z * ip); cp.h[3] = __float2bfloat16(p4.w * ip);
    *(ushort4*)(Un + base) = cu.s4;
    *(ushort4*)(Pn + base) = cp.s4;
}

// Stage 8 rows (4 KB) of a 64-row B tile per wave into LDS at l (4 async16).
// Linear layout with granule swizzle: stored granule g holds logical g^(r&7).
__device__ __forceinline__ void stage8(const unsigned short* __restrict__ g,
                                       unsigned short* l, int wv, int lane)
{
    const int lrow = lane >> 5;       // 0..1
    const int gcol = lane & 31;       // granule 0..31
    const int r0 = wv * 8;
    #pragma unroll
    for (int j = 0; j < 4; ++j) {
        const int rb = r0 + j * 2;
        const int r  = rb + lrow;
        const int gg = gcol ^ (r & 7);
        async16(g + (size_t)r * DDIM + gg * 8, l + (size_t)rb * DDIM);
    }
}

// Kernel 2: persistent-A GEMM + exp-rowsum + fused finalize.
// Co-designed structure (m201-adapted): 256 blocks x 512 thr (8 waves),
// 1 block/CU. Block = 256 rows x 1024 cols; wave = 32 rows (afr[2][8]=64
// regs direct from global). B quad-buffered 4 x 32 KB (128 KB LDS), 16
// tiles of 64 cols, 8-way wave reuse per staged byte. Slot i: counted
// vmcnt(8) (tile i landed, i+1/i+2 in flight -- never drains mid-loop) ->
// barrier -> stage tile i+3 into the buffer this barrier freed -> compute.
// Within a slot: 4 phases, ds_reads read-AHEAD one phase into ping-pong
// frag sets (plain C++ loads -> compiler's fine-grained lgkm waits; no
// R5-style read->wait->MFMA serialization), setprio(1) around each
// 16-MFMA cluster (waves drift between barriers -> role diversity).
__global__ __launch_bounds__(512, 2) void sim_exp_rowsum(
    const unsigned short* __restrict__ Un,
    const unsigned short* __restrict__ Pn,
    float* __restrict__ rowsum,
    const float* __restrict__ possim,
    int* __restrict__ counter,
    float* __restrict__ out)
{
    __shared__ __align__(16) unsigned short lds[65536];   // 128 KB: 4 x 32 KB B bufs
    __shared__ float ws8[8];
    __shared__ int ticket_s;

    const int tid  = threadIdx.x;
    const int lane = tid & 63;
    const int wv   = tid >> 6;          // 0..7, each wave owns 32 A-rows
    const int m = lane & 15;
    const int q = lane >> 4;

    const int stripe = blockIdx.x >> 3;   // 0..31  (256-row stripes)
    const int oct    = blockIdx.x & 7;    // 0..7   (1024-col groups == XCD)

    // ---- A-frags straight from global (one-time, L2/L3-hot) ----
    // row = stripe*256 + wv*32 + mf*16 + m ; bytes (ks*4+q)*16 (linear)
    const unsigned short* Arow = Un + (size_t)(stripe * 256 + wv * 32 + m) * DDIM;
    bf16x8 afr[2][8];
    #pragma unroll
    for (int t = 0; t < 2; ++t)
        #pragma unroll
        for (int ks = 0; ks < 8; ++ks)
            afr[t][ks] = *(const bf16x8*)(Arow + t * 16 * DDIM + (ks * 4 + q) * 8);

    // ---- B-frag addressing: addr = Bp + bb[par] + n*8192 + P*128 ----
    // reproduces row*512 + ((ks*4+q)^(m&7))*16 for row = n*16+m, ks = 2P+par.
    const int c10 = m & 3, c2 = (m >> 2) & 1;
    const unsigned bb0 = (unsigned)(m * 512 + ((q ^ c10) << 4) + ((0 ^ c2) << 6));
    const unsigned bb1 = (unsigned)(m * 512 + ((q ^ c10) << 4) + ((1 ^ c2) << 6));

    const unsigned short* Bglob = Pn + (size_t)(oct * 1024) * DDIM;
    float rowpart[2][4] = {{0.f, 0.f, 0.f, 0.f}, {0.f, 0.f, 0.f, 0.f}};

    // ---- Prologue: stage tiles 0..2, single full drain (also covers A) ----
    stage8(Bglob,                  lds,         wv, lane);
    stage8(Bglob + 64 * DDIM,      lds + 16384, wv, lane);
    stage8(Bglob + 128 * DDIM,     lds + 32768, wv, lane);
    asm volatile("s_waitcnt vmcnt(0)" ::: "memory");
    __builtin_amdgcn_s_barrier();

#define LOADPH(BP, P, F)                                                     \
    do {                                                                     \
        F[0] = *(const bf16x8*)((BP) + bb0 + 0 * 8192 + (P) * 128);          \
        F[1] = *(const bf16x8*)((BP) + bb0 + 1 * 8192 + (P) * 128);          \
        F[2] = *(const bf16x8*)((BP) + bb0 + 2 * 8192 + (P) * 128);          \
        F[3] = *(const bf16x8*)((BP) + bb0 + 3 * 8192 + (P) * 128);          \
        F[4] = *(const bf16x8*)((BP) + bb1 + 0 * 8192 + (P) * 128);          \
        F[5] = *(const bf16x8*)((BP) + bb1 + 1 * 8192 + (P) * 128);          \
        F[6] = *(const bf16x8*)((BP) + bb1 + 2 * 8192 + (P) * 128);          \
        F[7] = *(const bf16x8*)((BP) + bb1 + 3 * 8192 + (P) * 128);          \
    } while (0)

#define MMAPH(P, F)                                                          \
    do {                                                                     \
        __builtin_amdgcn_s_setprio(1);                                       \
        _Pragma("unroll")                                                    \
        for (int n = 0; n < 4; ++n) {                                        \
            acc[0][n] = __builtin_amdgcn_mfma_f32_16x16x32_bf16(             \
                afr[0][2 * (P)], F[n], acc[0][n], 0, 0, 0);                  \
            acc[1][n] = __builtin_amdgcn_mfma_f32_16x16x32_bf16(             \
                afr[1][2 * (P)], F[n], acc[1][n], 0, 0, 0);                  \
            acc[0][n] = __builtin_amdgcn_mfma_f32_16x16x32_bf16(             \
                afr[0][2 * (P) + 1], F[n + 4], acc[0][n], 0, 0, 0);          \
            acc[1][n] = __builtin_amdgcn_mfma_f32_16x16x32_bf16(             \
                afr[1][2 * (P) + 1], F[n + 4], acc[1][n], 0, 0, 0);          \
        }                                                                    \
        __builtin_amdgcn_s_setprio(0);                                       \
    } while (0)

    // ---- Main loop: 16 col-tiles of 64, quad-buffered, depth-2/3 ----
    for (int i = 0; i < 16; ++i) {
        if (i > 0) {
            // tile i landed; i+1 (and i+2 while still staging) stay in flight
            if (i <= 13)      asm volatile("s_waitcnt vmcnt(8)" ::: "memory");
            else if (i == 14) asm volatile("s_waitcnt vmcnt(4)" ::: "memory");
            else              asm volatile("s_waitcnt vmcnt(0)" ::: "memory");
            __builtin_amdgcn_s_barrier();   // frees buf (i-1)&3 == (i+3)&3
        }
        if (i + 3 < 16)
            stage8(Bglob + (size_t)(i + 3) * 64 * DDIM,
                   lds + ((i + 3) & 3) * 16384, wv, lane);

        const char* Bp = (const char*)lds + (i & 3) * 32768;
        floatx4 acc[2][4];
        #pragma unroll
        for (int t = 0; t < 2; ++t)
            #pragma unroll
            for (int n = 0; n < 4; ++n)
                acc[t][n] = {0.0f, 0.0f, 0.0f, 0.0f};

        bf16x8 fA[8], fB[8];
        LOADPH(Bp, 0, fA);      // phase 0 frags
        LOADPH(Bp, 1, fB);      // phase 1 frags in flight over phase-0 MFMAs
        MMAPH(0, fA);
        LOADPH(Bp, 2, fA);
        MMAPH(1, fB);
        LOADPH(Bp, 3, fB);
        MMAPH(2, fA);
        MMAPH(3, fB);

        // exp(5*sim) = 2^(sim*5*log2 e); C/D: col = m, row = q*4+r (+mf*16)
        #pragma unroll
        for (int t = 0; t < 2; ++t)
            #pragma unroll
            for (int n = 0; n < 4; ++n)
                #pragma unroll
                for (int r = 0; r < 4; ++r)
                    rowpart[t][r] += fexp2(acc[t][n][r] * 7.2134752044448169f);
    }
#undef LOADPH
#undef MMAPH

    // ---- Epilogue: reduce 16 column-lanes, one atomic per row per wave ----
    #pragma unroll
    for (int t = 0; t < 2; ++t) {
        #pragma unroll
        for (int r = 0; r < 4; ++r) {
            float s = rowpart[t][r];
            s += __shfl_xor(s, 1);
            s += __shfl_xor(s, 2);
            s += __shfl_xor(s, 4);
            s += __shfl_xor(s, 8);
            if (m == 0) {
                const int grow = stripe * 256 + wv * 32 + t * 16 + q * 4 + r;
                atomicAdd(&rowsum[grow], s);
            }
        }
    }

    // ---- Fused finalize: last block computes the loss ----
    __threadfence();
    __syncthreads();   // this block's atomics are visible
    if (tid == 0)
        ticket_s = __hip_atomic_fetch_add(counter, 1, __ATOMIC_ACQ_REL,
                                          __HIP_MEMORY_SCOPE_AGENT);
    __syncthreads();
    if (ticket_s == 255) {
        float part = 0.0f;
        for (int i = tid; i < NROWS; i += 512) {
            const float rs = __hip_atomic_load(&rowsum[i], __ATOMIC_RELAXED,
                                               __HIP_MEMORY_SCOPE_AGENT);
            part += __logf(rs) - 5.0f * possim[i];
        }
        #pragma unroll
        for (int d = 1; d < 64; d <<= 1) part += __shfl_xor(part, d);
        if (lane == 0) ws8[wv] = part;
        __syncthreads();
        if (tid == 0) {
            float tot = 0.0f;
            #pragma unroll
            for (int w = 0; w < 8; ++w) tot += ws8[w];
            out[0] = tot * (1.0f / (float)NROWS);
        }
    }
}

extern "C" void kernel_launch(void* const* d_in, const int* in_sizes, int n_in,
                              void* d_out, int out_size, void* d_ws, size_t ws_size,
                              hipStream_t stream) {
    const float* U = (const float*)d_in[0];
    const float* P = (const float*)d_in[1];
    float* out = (float*)d_out;
    char* ws = (char*)d_ws;
    // ws: Un bf16 (4 MB) | Pn bf16 (4 MB) | rowsum f32 (32 KB) | possim f32 (32 KB) | counter
    unsigned short* Un = (unsigned short*)ws;
    unsigned short* Pn = (unsigned short*)(ws + 4194304);
    float* rowsum = (float*)(ws + 8388608);
    float* possim = (float*)(ws + 8388608 + 32768);
    int* counter  = (int*)(ws + 8388608 + 65536);

    normalize_kernel<<<NROWS / 4, 256, 0, stream>>>(U, P, Un, Pn, possim, rowsum,
                                                    out, counter);
    sim_exp_rowsum<<<256, 512, 0, stream>>>(Un, Pn, rowsum, possim, counter, out);
}